// Round 1
// baseline (18856.432 us; speedup 1.0000x reference)
//
#include <hip/hip_runtime.h>
#include <stdint.h>

#define SEQ 8192
#define EMB 1024
#define HID 2048
#define NCH 256

#define SCAN_B 128                  // persistent blocks: 1 block/CU target halves FMA issue
#define SCAN_T 256                  // 4 waves/block (wave-level structure identical to R6)
#define ROWS_PB (HID / SCAN_B)      // 16 rows per block (4 per wave)
#define SENT 0xFFFFFFFFu            // poison: tanh never produces this pattern
#define NREP 4                      // ring replicas (spread L3 line ownership)
#define NSLOT 8                     // ring slots (skew<=1 proven; margin 4)

typedef unsigned uint4v __attribute__((ext_vector_type(4)));

// ---------------------------------------------------------------------------
// Generic fp32 "TN" GEMM: C[m][n] = bias[n] + dot(X[m][:], W[n][:])
// ---------------------------------------------------------------------------
__global__ __launch_bounds__(256) void gemm_tn(const float* __restrict__ X,
                                               const float* __restrict__ W,
                                               const float* __restrict__ bias,
                                               float* __restrict__ C,
                                               int M, int N, int K)
{
    __shared__ float Xs[16][68];
    __shared__ float Ws[16][68];
    const int m0 = blockIdx.x * 64, n0 = blockIdx.y * 64;
    const int tid  = threadIdx.x;
    const int lrow = tid >> 2;
    const int kq   = (tid & 3) * 4;
    const int tx   = tid & 15, ty = tid >> 4;
    float acc[4][4] = {};
    const float* Xp = X + (size_t)(m0 + lrow) * K + kq;
    const float* Wp = W + (size_t)(n0 + lrow) * K + kq;

    for (int k0 = 0; k0 < K; k0 += 16) {
        float4 xv = *(const float4*)(Xp + k0);
        float4 wv = *(const float4*)(Wp + k0);
        __syncthreads();
        Xs[kq+0][lrow] = xv.x; Xs[kq+1][lrow] = xv.y;
        Xs[kq+2][lrow] = xv.z; Xs[kq+3][lrow] = xv.w;
        Ws[kq+0][lrow] = wv.x; Ws[kq+1][lrow] = wv.y;
        Ws[kq+2][lrow] = wv.z; Ws[kq+3][lrow] = wv.w;
        __syncthreads();
#pragma unroll
        for (int kk = 0; kk < 16; ++kk) {
            float4 av = *(const float4*)&Xs[kk][ty * 4];
            float4 bv = *(const float4*)&Ws[kk][tx * 4];
            float a[4] = {av.x, av.y, av.z, av.w};
            float b[4] = {bv.x, bv.y, bv.z, bv.w};
#pragma unroll
            for (int i = 0; i < 4; ++i)
#pragma unroll
                for (int j = 0; j < 4; ++j)
                    acc[i][j] += a[i] * b[j];
        }
    }
#pragma unroll
    for (int i = 0; i < 4; ++i) {
        const int m = m0 + ty * 4 + i;
#pragma unroll
        for (int j = 0; j < 4; ++j) {
            const int n = n0 + tx * 4 + j;
            C[(size_t)m * N + n] = acc[i][j] + bias[n];
        }
    }
}

// tanh(x) = 1 - 2/(exp2(2x*log2e)+1); ~1e-6 rel error, finite everywhere.
__device__ __forceinline__ float fast_tanh(float x)
{
    float e = __builtin_amdgcn_exp2f(x * 2.885390081777927f);
    return 1.0f - 2.0f * __builtin_amdgcn_rcpf(e + 1.0f);
}

// ---------------------------------------------------------------------------
// Persistent RNN scan, R7:
//   R6 compute (wave owns 4 rows; 128 weights/thread in regs; paired
//   butterfly reduce) + ring-replicated poison exchange, with three changes:
//
//   (1) 128 blocks x 256 threads (same 512 waves, same wave-level code).
//       1 wave/SIMD on ~128 CUs halves the per-SIMD FMA-issue phase
//       (512 -> 256 cy). Worst-case packing (2 blocks/CU) == old layout.
//   (2) Counted-vmcnt poll prefetch (T4 pattern): the poll loads for slot
//       (t+1)&7 are ISSUED before the 9 producer stores of step t. At the
//       top of step t+1, s_waitcnt vmcnt(9) is guaranteed to have retired
//       the prefetch (>=9 vmem ops were issued after it; vmcnt completion
//       is in issue order), WITHOUT draining the store-acks. Late-arriving
//       (step-gating) blocks find data already in registers. Registers are
//       pre-set to SENT, so any compiler interference (extra vmem ops only
//       lengthen the wait; spills capture SENT) degrades to the full-poll
//       path -- never accepts garbage.
//   (3) Tight full-poll: one asm global_load_dwordx4 pair with sc0 sc1
//       (L1+L2 bypass -> coherent L3 read; per-dword atomicity is
//       sufficient, each word is independently poison-or-final), vmcnt(0)
//       inside the same asm block (value def-use tie => no reordering
//       hazard), no s_sleep. Producer issues all NREP signal stores first,
//       then poisons, then the plain H row (only read by epilogue GEMM).
//
//   Slot-reuse/poison-distance argument unchanged from R6 (skew<=1; poison
//   at distance 4, reuse at distance 8; same-thread same-address stores are
//   coherence-ordered).
// ---------------------------------------------------------------------------
__global__ __launch_bounds__(SCAN_T, 1) void rnn_scan(
    const int*  __restrict__ seq,
    const float* __restrict__ waa,
    const float* __restrict__ P,
    float* __restrict__ H,                 // (SEQ+1) x HID; plain (not polled)
    unsigned* __restrict__ ring)           // NREP x NSLOT x HID
{
    const int b    = blockIdx.x;
    const int tid  = threadIdx.x;
    const int wv   = tid >> 6;        // wave id 0..3
    const int lane = tid & 63;
    const int R0   = b * ROWS_PB + wv * 4;   // first of this wave's 4 rows
    const int rep  = b & (NREP - 1);

    __shared__ float hbuf[2][HID];    // 16 KB parity double-buffer

    // One-time weight load: w[i][4j+e] = waa[R0+i][256j+4*lane+e].
    float w0[32], w1[32], w2[32], w3[32];
#pragma unroll
    for (int j = 0; j < 8; ++j) {
        const float* base = waa + 256 * j + 4 * lane;
        float4 a = *(const float4*)(base + (size_t)(R0 + 0) * HID);
        float4 c = *(const float4*)(base + (size_t)(R0 + 1) * HID);
        float4 d = *(const float4*)(base + (size_t)(R0 + 2) * HID);
        float4 e = *(const float4*)(base + (size_t)(R0 + 3) * HID);
        w0[4*j+0]=a.x; w0[4*j+1]=a.y; w0[4*j+2]=a.z; w0[4*j+3]=a.w;
        w1[4*j+0]=c.x; w1[4*j+1]=c.y; w1[4*j+2]=c.z; w1[4*j+3]=c.w;
        w2[4*j+0]=d.x; w2[4*j+1]=d.y; w2[4*j+2]=d.z; w2[4*j+3]=d.w;
        w3[4*j+0]=e.x; w3[4*j+1]=e.y; w3[4*j+2]=e.z; w3[4*j+3]=e.w;
    }
#pragma unroll
    for (int k = 0; k < 32; ++k) {
        asm volatile("" : "+v"(w0[k])); asm volatile("" : "+v"(w1[k]));
        asm volatile("" : "+v"(w2[k])); asm volatile("" : "+v"(w3[k]));
    }

    unsigned* myring = ring + (size_t)rep * NSLOT * HID;
    const uint4v SV = {SENT, SENT, SENT, SENT};
    uint4v v0 = SV, v1 = SV;          // poll registers (persist across steps)

#pragma unroll 1
    for (int t = 0; t < SEQ; ++t) {
        // xa for this step (read-only, cached) -- overlaps the poll.
        const int ch = seq[t];
        float xav = 0.f;
        if (lane < 4) xav = P[(size_t)ch * HID + R0 + lane];

        // --- counted wait on the prefetch issued at the end of step t-1 ---
        // >=9 vmem ops (producer stores [+xa load]) were issued after the
        // prefetch, so vmcnt(9) implies the prefetch retired. "+v" ties the
        // check's data-dependency to this asm so the compare cannot be
        // hoisted above the wait.
        asm volatile("s_waitcnt vmcnt(9)" : "+v"(v0), "+v"(v1) : : "memory");
        if (v0.x == SENT || v0.y == SENT || v0.z == SENT || v0.w == SENT ||
            v1.x == SENT || v1.y == SENT || v1.z == SENT || v1.w == SENT) {
            // --- full poll: tight loop, one 32B coherent read per pass ---
            const unsigned* pp =
                myring + (size_t)(t & (NSLOT - 1)) * HID + tid * 8;
            do {
                asm volatile("s_waitcnt vmcnt(0)\n\t"
                             "global_load_dwordx4 %0, %2, off sc0 sc1\n\t"
                             "global_load_dwordx4 %1, %2, off offset:16 sc0 sc1\n\t"
                             "s_waitcnt vmcnt(0)"
                             : "+v"(v0), "+v"(v1) : "v"(pp) : "memory");
            } while (v0.x == SENT || v0.y == SENT || v0.z == SENT || v0.w == SENT ||
                     v1.x == SENT || v1.y == SENT || v1.z == SENT || v1.w == SENT);
        }
        *(uint4v*)&hbuf[t & 1][tid * 8]     = v0;
        *(uint4v*)&hbuf[t & 1][tid * 8 + 4] = v1;
        __syncthreads();

        // --- 8 conflict-free b128 reads, 128 FMAs over 4 rows (R6) ---
        float a0 = 0.f, a1 = 0.f, a2 = 0.f, a3 = 0.f;
        const float* hb = &hbuf[t & 1][4 * lane];
#pragma unroll
        for (int j = 0; j < 8; ++j) {
            float4 hv = *(const float4*)(hb + 256 * j);
            a0 += w0[4*j+0]*hv.x + w0[4*j+1]*hv.y + w0[4*j+2]*hv.z + w0[4*j+3]*hv.w;
            a1 += w1[4*j+0]*hv.x + w1[4*j+1]*hv.y + w1[4*j+2]*hv.z + w1[4*j+3]*hv.w;
            a2 += w2[4*j+0]*hv.x + w2[4*j+1]*hv.y + w2[4*j+2]*hv.z + w2[4*j+3]*hv.w;
            a3 += w3[4*j+0]*hv.x + w3[4*j+1]*hv.y + w3[4*j+2]*hv.z + w3[4*j+3]*hv.w;
        }
        // Paired butterfly: row (lane&3)'s full sum ends in lane l.
        a0 += __shfl_xor(a0, 1, 64);
        a1 += __shfl_xor(a1, 1, 64);
        a2 += __shfl_xor(a2, 1, 64);
        a3 += __shfl_xor(a3, 1, 64);
        float m01 = (lane & 1) ? a1 : a0;
        float m23 = (lane & 1) ? a3 : a2;
        m01 += __shfl_xor(m01, 2, 64);
        m23 += __shfl_xor(m23, 2, 64);
        float m = (lane & 2) ? m23 : m01;
        m += __shfl_xor(m, 4, 64);
        m += __shfl_xor(m, 8, 64);
        m += __shfl_xor(m, 16, 64);
        m += __shfl_xor(m, 32, 64);

        // --- prefetch next slot BEFORE the producer stores, so the stores
        //     pad the vmcnt window that the next step counts against ---
        if (t + 1 < SEQ) {
            const unsigned* pn =
                myring + (size_t)((t + 1) & (NSLOT - 1)) * HID + tid * 8;
            v0 = SV; v1 = SV;   // hazard-safe default: any early read => retry
            asm volatile("global_load_dwordx4 %0, %2, off sc0 sc1\n\t"
                         "global_load_dwordx4 %1, %2, off offset:16 sc0 sc1"
                         : "+v"(v0), "+v"(v1) : "v"(pn) : "memory");
        }

        if (lane < 4) {
            float hn = fast_tanh(xav + m);
            const unsigned hu = __float_as_uint(hn);
            const int row = R0 + lane;
            const int s1 = (t + 1) & (NSLOT - 1);
            const int s5 = (t + 5) & (NSLOT - 1);
            // signals to ALL replicas first (consumer-critical), ...
#pragma unroll
            for (int r = 0; r < NREP; ++r)
                __hip_atomic_store(ring + ((size_t)r * NSLOT + s1) * HID + row,
                                   hu, __ATOMIC_RELAXED,
                                   __HIP_MEMORY_SCOPE_AGENT);
            // ... then poisons (needed 4 steps out), then plain H row.
#pragma unroll
            for (int r = 0; r < NREP; ++r)
                __hip_atomic_store(ring + ((size_t)r * NSLOT + s5) * HID + row,
                                   SENT, __ATOMIC_RELAXED,
                                   __HIP_MEMORY_SCOPE_AGENT);
            H[(size_t)(t + 1) * HID + row] = hn;   // epilogue GEMM input
        }
        // store IS the signal; unique addresses per slot -> race-free
    }
}

__global__ void copy_h(const float* __restrict__ src, float* __restrict__ dst)
{
    int i = blockIdx.x * blockDim.x + threadIdx.x;
    if (i < HID) dst[i] = src[i];
}

// ---------------------------------------------------------------------------
extern "C" void kernel_launch(void* const* d_in, const int* in_sizes, int n_in,
                              void* d_out, int out_size, void* d_ws, size_t ws_size,
                              hipStream_t stream)
{
    const int*   seq  = (const int*)  d_in[0];
    const float* emb  = (const float*)d_in[1];
    const float* wax  = (const float*)d_in[2];
    const float* waxb = (const float*)d_in[3];
    const float* waa  = (const float*)d_in[4];
    const float* wya  = (const float*)d_in[5];
    const float* wyab = (const float*)d_in[6];
    float* out = (float*)d_out;

    // ws layout: H[(SEQ+1)][HID] fp32 | P[NCH][HID] fp32 | ring[4][8][HID] u32
    float*    H    = (float*)d_ws;
    float*    P    = (float*)((char*)d_ws + (size_t)(SEQ + 1) * HID * sizeof(float));
    unsigned* ring = (unsigned*)(P + (size_t)NCH * HID);

    // Re-init every call: ring all-poison, then slot 0 of each replica = h0 = 0.
    (void)hipMemsetAsync(ring, 0xFF, (size_t)NREP * NSLOT * HID * sizeof(unsigned), stream);
    for (int r = 0; r < NREP; ++r)
        (void)hipMemsetAsync(ring + (size_t)r * NSLOT * HID, 0,
                             HID * sizeof(unsigned), stream);

    // P = emb @ wax^T + wax_b   (M=256, N=2048, K=1024)
    dim3 gA(NCH / 64, HID / 64);
    gemm_tn<<<gA, 256, 0, stream>>>(emb, wax, waxb, P, NCH, HID, EMB);

    // Sequential recurrence (persistent, ring-replicated poison sync).
    rnn_scan<<<SCAN_B, SCAN_T, 0, stream>>>(seq, waa, P, H, ring);

    // out = H[1..SEQ] @ wya^T + wya_b   (M=8192, N=256, K=2048)
    dim3 gC(SEQ / 64, NCH / 64);
    gemm_tn<<<gC, 256, 0, stream>>>(H + HID, wya, wyab, out, SEQ, NCH, HID);

    // h_final = H[SEQ] -> tail of d_out
    copy_h<<<(HID + 255) / 256, 256, 0, stream>>>(H + (size_t)SEQ * HID,
                                                  out + (size_t)SEQ * NCH);
}

// Round 3
// 15621.983 us; speedup vs baseline: 1.2070x; 1.2070x over previous
//
#include <hip/hip_runtime.h>
#include <stdint.h>

#define SEQ 8192
#define EMB 1024
#define HID 2048
#define NCH 256

#define SCAN_B 64                   // persistent blocks (co-resident, proven R1-R6)
#define SCAN_T 512                  // 8 waves/block
#define ROWS_PB (HID / SCAN_B)      // 32 rows per block (4 per wave)
#define SENT 0xFFFFFFFFu            // poison: tanh never produces this pattern
#define NREP 4                      // ring replicas (spread L3 line ownership)
#define NSLOT 8                     // ring slots (skew<=1 proven; margin 4)

typedef unsigned uint4v __attribute__((ext_vector_type(4)));

// ---------------------------------------------------------------------------
// Generic fp32 "TN" GEMM: C[m][n] = bias[n] + dot(X[m][:], W[n][:])
// ---------------------------------------------------------------------------
__global__ __launch_bounds__(256) void gemm_tn(const float* __restrict__ X,
                                               const float* __restrict__ W,
                                               const float* __restrict__ bias,
                                               float* __restrict__ C,
                                               int M, int N, int K)
{
    __shared__ float Xs[16][68];
    __shared__ float Ws[16][68];
    const int m0 = blockIdx.x * 64, n0 = blockIdx.y * 64;
    const int tid  = threadIdx.x;
    const int lrow = tid >> 2;
    const int kq   = (tid & 3) * 4;
    const int tx   = tid & 15, ty = tid >> 4;
    float acc[4][4] = {};
    const float* Xp = X + (size_t)(m0 + lrow) * K + kq;
    const float* Wp = W + (size_t)(n0 + lrow) * K + kq;

    for (int k0 = 0; k0 < K; k0 += 16) {
        float4 xv = *(const float4*)(Xp + k0);
        float4 wv = *(const float4*)(Wp + k0);
        __syncthreads();
        Xs[kq+0][lrow] = xv.x; Xs[kq+1][lrow] = xv.y;
        Xs[kq+2][lrow] = xv.z; Xs[kq+3][lrow] = xv.w;
        Ws[kq+0][lrow] = wv.x; Ws[kq+1][lrow] = wv.y;
        Ws[kq+2][lrow] = wv.z; Ws[kq+3][lrow] = wv.w;
        __syncthreads();
#pragma unroll
        for (int kk = 0; kk < 16; ++kk) {
            float4 av = *(const float4*)&Xs[kk][ty * 4];
            float4 bv = *(const float4*)&Ws[kk][tx * 4];
            float a[4] = {av.x, av.y, av.z, av.w};
            float b[4] = {bv.x, bv.y, bv.z, bv.w};
#pragma unroll
            for (int i = 0; i < 4; ++i)
#pragma unroll
                for (int j = 0; j < 4; ++j)
                    acc[i][j] += a[i] * b[j];
        }
    }
#pragma unroll
    for (int i = 0; i < 4; ++i) {
        const int m = m0 + ty * 4 + i;
#pragma unroll
        for (int j = 0; j < 4; ++j) {
            const int n = n0 + tx * 4 + j;
            C[(size_t)m * N + n] = acc[i][j] + bias[n];
        }
    }
}

// tanh(x) = 1 - 2/(exp2(2x*log2e)+1); ~1e-6 rel error, finite everywhere.
__device__ __forceinline__ float fast_tanh(float x)
{
    float e = __builtin_amdgcn_exp2f(x * 2.885390081777927f);
    return 1.0f - 2.0f * __builtin_amdgcn_rcpf(e + 1.0f);
}

// ---------------------------------------------------------------------------
// Persistent RNN scan, R9 = R6 dataflow (all rows via ring) with the per-step
// __syncthreads() REPLACED by per-chunk LDS flags:
//
//   - Wave w stages chunk w (rows [256w,256w+256), thread window [4tid,4tid+4))
//     from ring slot t&7, fences lgkmcnt(0), then lane 0 publishes
//     flg[t&1][w] = t.  The compute loop gates chunk j's 16 FMAs on
//     flg[t&1][j] == t (volatile LDS spin, broadcast read, + asm memory
//     clobber so hbuf reads cannot be hoisted above the spin).
//     Accumulation order j=0..7 unchanged -> bit-identical results.
//   - Parity safety: a wave stages step t+2 into hbuf[t&1] only after all 8
//     waves published parity-(t+1) flags; each publish is lgkm-fenced after
//     that wave's compute-t reads of hbuf[t&1] completed.  So no wave can
//     overwrite a buffer any sibling still reads.  Intra-block wave skew
//     <= 1; global skew <= 1 (staging t requires h(t) fully present =>
//     every wave of every block finished compute t-1).  Ring poison at
//     distance 5 / reuse at distance 8 margins are therefore unchanged
//     from the proven R6 protocol.
//   - No per-step s_barrier => no forced s_waitcnt vmcnt(0) drain of the 9
//     cross-XCD store acks each step, and compute overlaps late chunks.
//   - Poll: single asm block {load dwordx4 sc0 sc1; vmcnt(0)} per round --
//     load and its waitcnt NEVER split across asm blocks (R8's crash was an
//     in-flight load whose destination registers the compiler reused).
//     No leading drain: the first round's vmcnt(0) overlaps the store-ack
//     drain with the load's own latency.  No s_sleep.
// ---------------------------------------------------------------------------
__global__ __launch_bounds__(SCAN_T, 2) void rnn_scan(
    const int*  __restrict__ seq,
    const float* __restrict__ waa,
    const float* __restrict__ P,
    float* __restrict__ H,                 // (SEQ+1) x HID; plain (not polled)
    unsigned* __restrict__ ring)           // NREP x NSLOT x HID
{
    const int b    = blockIdx.x;
    const int tid  = threadIdx.x;
    const int wv   = tid >> 6;        // wave id 0..7
    const int lane = tid & 63;
    const int R0   = b * ROWS_PB + wv * 4;   // first of this wave's 4 rows
    const int rep  = b & (NREP - 1);

    __shared__ float hbuf[2][HID];    // 16 KB parity double-buffer
    __shared__ int   flg[2][8];       // per-parity, per-chunk "staged@step"

    // One-time weight load: w[i][4j+e] = waa[R0+i][256j+4*lane+e].
    float w0[32], w1[32], w2[32], w3[32];
#pragma unroll
    for (int j = 0; j < 8; ++j) {
        const float* base = waa + 256 * j + 4 * lane;
        float4 a = *(const float4*)(base + (size_t)(R0 + 0) * HID);
        float4 c = *(const float4*)(base + (size_t)(R0 + 1) * HID);
        float4 d = *(const float4*)(base + (size_t)(R0 + 2) * HID);
        float4 e = *(const float4*)(base + (size_t)(R0 + 3) * HID);
        w0[4*j+0]=a.x; w0[4*j+1]=a.y; w0[4*j+2]=a.z; w0[4*j+3]=a.w;
        w1[4*j+0]=c.x; w1[4*j+1]=c.y; w1[4*j+2]=c.z; w1[4*j+3]=c.w;
        w2[4*j+0]=d.x; w2[4*j+1]=d.y; w2[4*j+2]=d.z; w2[4*j+3]=d.w;
        w3[4*j+0]=e.x; w3[4*j+1]=e.y; w3[4*j+2]=e.z; w3[4*j+3]=e.w;
    }
#pragma unroll
    for (int k = 0; k < 32; ++k) {
        asm volatile("" : "+v"(w0[k])); asm volatile("" : "+v"(w1[k]));
        asm volatile("" : "+v"(w2[k])); asm volatile("" : "+v"(w3[k]));
    }

    if (tid < 16) ((int*)flg)[tid] = -1;
    __syncthreads();                  // the ONLY barrier (flag init)

    unsigned* myring = ring + (size_t)rep * NSLOT * HID;

#pragma unroll 1
    for (int t = 0; t < SEQ; ++t) {
        // xa for this step (read-only, cached) -- overlaps the poll.
        const int ch = seq[t];
        float xav = 0.f;
        if (lane < 4) xav = P[(size_t)ch * HID + R0 + lane];

        // --- poll my 4 words of slot t&7; load+wait in ONE asm block ---
        uint4v v;
        const unsigned* pp = myring + (size_t)(t & (NSLOT - 1)) * HID + tid * 4;
        do {
            asm volatile("global_load_dwordx4 %0, %1, off sc0 sc1\n\t"
                         "s_waitcnt vmcnt(0)"
                         : "=v"(v) : "v"(pp) : "memory");
        } while (v.x == SENT || v.y == SENT || v.z == SENT || v.w == SENT);
        *(uint4v*)&hbuf[t & 1][tid * 4] = v;   // 16B stride: conflict-free

        // publish chunk wv for parity t&1 (data-before-flag via lgkmcnt(0))
        asm volatile("s_waitcnt lgkmcnt(0)" ::: "memory");
        if (lane == 0) *(volatile int*)&flg[t & 1][wv] = t;

        // --- per-chunk gated compute: 8x {spin flag; b128 read; 16 FMA} ---
        float a0 = 0.f, a1 = 0.f, a2 = 0.f, a3 = 0.f;
        const float* hb = &hbuf[t & 1][4 * lane];
#pragma unroll
        for (int j = 0; j < 8; ++j) {
            while (*(volatile int*)&flg[t & 1][j] != t) { }
            asm volatile("" ::: "memory");   // no hbuf-read hoist above spin
            float4 hv = *(const float4*)(hb + 256 * j);
            a0 += w0[4*j+0]*hv.x + w0[4*j+1]*hv.y + w0[4*j+2]*hv.z + w0[4*j+3]*hv.w;
            a1 += w1[4*j+0]*hv.x + w1[4*j+1]*hv.y + w1[4*j+2]*hv.z + w1[4*j+3]*hv.w;
            a2 += w2[4*j+0]*hv.x + w2[4*j+1]*hv.y + w2[4*j+2]*hv.z + w2[4*j+3]*hv.w;
            a3 += w3[4*j+0]*hv.x + w3[4*j+1]*hv.y + w3[4*j+2]*hv.z + w3[4*j+3]*hv.w;
        }
        // Paired butterfly: row (lane&3)'s full sum ends in lane l.
        a0 += __shfl_xor(a0, 1, 64);
        a1 += __shfl_xor(a1, 1, 64);
        a2 += __shfl_xor(a2, 1, 64);
        a3 += __shfl_xor(a3, 1, 64);
        float m01 = (lane & 1) ? a1 : a0;
        float m23 = (lane & 1) ? a3 : a2;
        m01 += __shfl_xor(m01, 2, 64);
        m23 += __shfl_xor(m23, 2, 64);
        float m = (lane & 2) ? m23 : m01;
        m += __shfl_xor(m, 4, 64);
        m += __shfl_xor(m, 8, 64);
        m += __shfl_xor(m, 16, 64);
        m += __shfl_xor(m, 32, 64);

        if (lane < 4) {
            float hn = fast_tanh(xav + m);
            const unsigned hu = __float_as_uint(hn);
            const int row = R0 + lane;
            const int s1 = (t + 1) & (NSLOT - 1);
            const int s5 = (t + 5) & (NSLOT - 1);
            // signals to ALL replicas first (consumer-critical), ...
#pragma unroll
            for (int r = 0; r < NREP; ++r)
                __hip_atomic_store(ring + ((size_t)r * NSLOT + s1) * HID + row,
                                   hu, __ATOMIC_RELAXED,
                                   __HIP_MEMORY_SCOPE_AGENT);
            // ... then poisons (needed 4 steps out), then plain H row.
#pragma unroll
            for (int r = 0; r < NREP; ++r)
                __hip_atomic_store(ring + ((size_t)r * NSLOT + s5) * HID + row,
                                   SENT, __ATOMIC_RELAXED,
                                   __HIP_MEMORY_SCOPE_AGENT);
            H[(size_t)(t + 1) * HID + row] = hn;   // epilogue GEMM input
        }
        // store IS the signal; unique addresses per slot -> race-free
    }
}

__global__ void copy_h(const float* __restrict__ src, float* __restrict__ dst)
{
    int i = blockIdx.x * blockDim.x + threadIdx.x;
    if (i < HID) dst[i] = src[i];
}

// ---------------------------------------------------------------------------
extern "C" void kernel_launch(void* const* d_in, const int* in_sizes, int n_in,
                              void* d_out, int out_size, void* d_ws, size_t ws_size,
                              hipStream_t stream)
{
    const int*   seq  = (const int*)  d_in[0];
    const float* emb  = (const float*)d_in[1];
    const float* wax  = (const float*)d_in[2];
    const float* waxb = (const float*)d_in[3];
    const float* waa  = (const float*)d_in[4];
    const float* wya  = (const float*)d_in[5];
    const float* wyab = (const float*)d_in[6];
    float* out = (float*)d_out;

    // ws layout: H[(SEQ+1)][HID] fp32 | P[NCH][HID] fp32 | ring[4][8][HID] u32
    float*    H    = (float*)d_ws;
    float*    P    = (float*)((char*)d_ws + (size_t)(SEQ + 1) * HID * sizeof(float));
    unsigned* ring = (unsigned*)(P + (size_t)NCH * HID);

    // Re-init every call: ring all-poison, then slot 0 of each replica = h0 = 0.
    (void)hipMemsetAsync(ring, 0xFF, (size_t)NREP * NSLOT * HID * sizeof(unsigned), stream);
    for (int r = 0; r < NREP; ++r)
        (void)hipMemsetAsync(ring + (size_t)r * NSLOT * HID, 0,
                             HID * sizeof(unsigned), stream);

    // P = emb @ wax^T + wax_b   (M=256, N=2048, K=1024)
    dim3 gA(NCH / 64, HID / 64);
    gemm_tn<<<gA, 256, 0, stream>>>(emb, wax, waxb, P, NCH, HID, EMB);

    // Sequential recurrence (persistent, flag-dataflow + ring poison sync).
    rnn_scan<<<SCAN_B, SCAN_T, 0, stream>>>(seq, waa, P, H, ring);

    // out = H[1..SEQ] @ wya^T + wya_b   (M=8192, N=256, K=2048)
    dim3 gC(SEQ / 64, NCH / 64);
    gemm_tn<<<gC, 256, 0, stream>>>(H + HID, wya, wyab, out, SEQ, NCH, HID);

    // h_final = H[SEQ] -> tail of d_out
    copy_h<<<(HID + 255) / 256, 256, 0, stream>>>(H + (size_t)SEQ * HID,
                                                  out + (size_t)SEQ * NCH);
}